// Round 1
// baseline (613.852 us; speedup 1.0000x reference)
//
#include <hip/hip_runtime.h>

#define T_ 2048
#define B_ 2
#define H_ 12
#define C_ 768
#define M_ 4096  // B*T

typedef __attribute__((ext_vector_type(4))) float f32x4;
typedef __attribute__((ext_vector_type(8))) __bf16 bf16x8;
typedef __attribute__((ext_vector_type(4))) __bf16 bf16x4;

// ---------------------------------------------------------------------------
// GEMM: C[M,N] = A[M,K] * B[N,K]^T   (fp32 in, bf16 MFMA, fp32 out)
// 128x128 tile, BK=32, 4 waves in 2x2, each wave 64x64 = 4x4 frags of 16x16.
// ---------------------------------------------------------------------------
__global__ __launch_bounds__(256) void gemm_bt(const float* __restrict__ A,
                                               const float* __restrict__ Bm,
                                               float* __restrict__ C,
                                               int M, int N, int K) {
  // +8 pad: row stride 80B -> 20 banks -> 2-way (free); keeps 16B alignment.
  __shared__ __align__(16) __bf16 sA[128][40];
  __shared__ __align__(16) __bf16 sB[128][40];
  const int tid = threadIdx.x;
  const int m0 = blockIdx.y * 128, n0 = blockIdx.x * 128;
  const int lane = tid & 63, w = tid >> 6;
  const int wr = w >> 1, wc = w & 1;
  const int fr = lane & 15;          // A frag row / B frag col
  const int ko = (lane >> 4) << 3;   // k offset: 0,8,16,24
  f32x4 acc[4][4] = {};
  for (int k0 = 0; k0 < K; k0 += 32) {
#pragma unroll
    for (int i = 0; i < 4; ++i) {
      int f = tid + (i << 8);
      int row = f >> 3, c4 = (f & 7) << 2;
      f32x4 av = *(const f32x4*)(A + (size_t)(m0 + row) * K + k0 + c4);
      f32x4 bv = *(const f32x4*)(Bm + (size_t)(n0 + row) * K + k0 + c4);
      bf16x4 ah, bh;
#pragma unroll
      for (int j = 0; j < 4; ++j) { ah[j] = (__bf16)av[j]; bh[j] = (__bf16)bv[j]; }
      *(bf16x4*)&sA[row][c4] = ah;
      *(bf16x4*)&sB[row][c4] = bh;
    }
    __syncthreads();
    bf16x8 a[4], b[4];
#pragma unroll
    for (int m = 0; m < 4; ++m) a[m] = *(const bf16x8*)&sA[wr * 64 + m * 16 + fr][ko];
#pragma unroll
    for (int n = 0; n < 4; ++n) b[n] = *(const bf16x8*)&sB[wc * 64 + n * 16 + fr][ko];
#pragma unroll
    for (int m = 0; m < 4; ++m)
#pragma unroll
      for (int n = 0; n < 4; ++n)
        acc[m][n] = __builtin_amdgcn_mfma_f32_16x16x32_bf16(a[m], b[n], acc[m][n], 0, 0, 0);
    __syncthreads();
  }
  // C/D layout (HW-verified): col = lane&15, row = (lane>>4)*4 + j
  const int orow = (lane >> 4) << 2, ocol = lane & 15;
#pragma unroll
  for (int m = 0; m < 4; ++m)
#pragma unroll
    for (int n = 0; n < 4; ++n) {
      int r = m0 + wr * 64 + m * 16 + orow;
      int c = n0 + wc * 64 + n * 16 + ocol;
#pragma unroll
      for (int j = 0; j < 4; ++j) C[(size_t)(r + j) * N + c] = acc[m][n][j];
    }
}

// ---------------------------------------------------------------------------
// corr: cw[b,h,tau] = (1/(64*(temp+eps))) * sum_{t>=tau} sum_d q[t,d]*k[t-tau,d]
// block = (tau-block of 64) x h x b.  thread: g=tid&15 -> tau quad, h8=tid>>4 -> t chunk.
// ---------------------------------------------------------------------------
__global__ __launch_bounds__(256) void corr_k(const float* __restrict__ qkv,
                                              const float* __restrict__ temp,
                                              float* __restrict__ cw) {
  __shared__ __align__(16) float sq[64][68];
  __shared__ __align__(16) float sk[128][68];
  const int tid = threadIdx.x;
  const int jb = blockIdx.x, h = blockIdx.y, b = blockIdx.z;
  const int tau0 = jb << 6;
  const int g = tid & 15, h8 = tid >> 4;
  const float* qb = qkv + (size_t)b * T_ * 2304 + h * 64;
  const float* kp = qb + 768;
  f32x4 ac0 = {}, ac1 = {}, ac2 = {}, ac3 = {};
  for (int t0 = tau0; t0 < T_; t0 += 64) {
#pragma unroll
    for (int i = 0; i < 4; ++i) {  // stage q[t0..t0+64) x 64d
      int f = tid + (i << 8);
      int row = f >> 4, c4 = (f & 15) << 2;
      *(f32x4*)&sq[row][c4] = *(const f32x4*)(qb + (size_t)(t0 + row) * 2304 + c4);
    }
    const int cbase = t0 - tau0 - 63;
#pragma unroll
    for (int i = 0; i < 8; ++i) {  // stage k window, zero-filled outside [0,T)
      int f = tid + (i << 8);
      int row = f >> 4, c4 = (f & 15) << 2;
      int c = cbase + row;
      f32x4 v = {};
      if (c >= 0 && c < T_) v = *(const f32x4*)(kp + (size_t)c * 2304 + c4);
      *(f32x4*)&sk[row][c4] = v;
    }
    __syncthreads();
    const int kb = ((h8 - g) << 2) + 60;  // k row = kb + tt + 3 - r
#pragma unroll 4
    for (int d0 = 0; d0 < 64; d0 += 4) {
      f32x4 q0 = *(const f32x4*)&sq[(h8 << 2) + 0][d0];
      f32x4 q1 = *(const f32x4*)&sq[(h8 << 2) + 1][d0];
      f32x4 q2 = *(const f32x4*)&sq[(h8 << 2) + 2][d0];
      f32x4 q3 = *(const f32x4*)&sq[(h8 << 2) + 3][d0];
      f32x4 k0 = *(const f32x4*)&sk[kb + 0][d0];
      f32x4 k1 = *(const f32x4*)&sk[kb + 1][d0];
      f32x4 k2 = *(const f32x4*)&sk[kb + 2][d0];
      f32x4 k3 = *(const f32x4*)&sk[kb + 3][d0];
      f32x4 k4 = *(const f32x4*)&sk[kb + 4][d0];
      f32x4 k5 = *(const f32x4*)&sk[kb + 5][d0];
      f32x4 k6 = *(const f32x4*)&sk[kb + 6][d0];
      ac3 += q0 * k0 + q1 * k1 + q2 * k2 + q3 * k3;  // r=3: tau = tau0+4g+3
      ac2 += q0 * k1 + q1 * k2 + q2 * k3 + q3 * k4;
      ac1 += q0 * k2 + q1 * k3 + q2 * k4 + q3 * k5;
      ac0 += q0 * k3 + q1 * k4 + q2 * k5 + q3 * k6;  // r=0
    }
    __syncthreads();
  }
  float a0 = ac0[0] + ac0[1] + ac0[2] + ac0[3];
  float a1 = ac1[0] + ac1[1] + ac1[2] + ac1[3];
  float a2 = ac2[0] + ac2[1] + ac2[2] + ac2[3];
  float a3 = ac3[0] + ac3[1] + ac3[2] + ac3[3];
  float* red = &sq[0][0];  // [g*4+r][17 stride] x h8
  red[((g << 2) + 0) * 17 + h8] = a0;
  red[((g << 2) + 1) * 17 + h8] = a1;
  red[((g << 2) + 2) * 17 + h8] = a2;
  red[((g << 2) + 3) * 17 + h8] = a3;
  __syncthreads();
  if (tid < 64) {
    float s = 0;
#pragma unroll
    for (int hh = 0; hh < 16; ++hh) s += red[tid * 17 + hh];
    float scale = 1.0f / (64.0f * (temp[0] + 1e-6f));
    cw[((size_t)b * H_ + h) * T_ + tau0 + tid] = s * scale;
  }
}

// ---------------------------------------------------------------------------
// softmax prep per (b,h): M = max w; e = exp(w-M); Z[t] = prefix sum of e.
// ---------------------------------------------------------------------------
__global__ __launch_bounds__(256) void soft_k(const float* __restrict__ cw,
                                              float* __restrict__ ee,
                                              float* __restrict__ zz) {
  const int bh = blockIdx.x, tid = threadIdx.x;
  const int lane = tid & 63, wid = tid >> 6;
  const float* w = cw + (size_t)bh * T_;
  float v[8];
#pragma unroll
  for (int i = 0; i < 8; ++i) v[i] = w[(tid << 3) + i];
  float m = v[0];
#pragma unroll
  for (int i = 1; i < 8; ++i) m = fmaxf(m, v[i]);
#pragma unroll
  for (int off = 1; off < 64; off <<= 1) m = fmaxf(m, __shfl_xor(m, off));
  __shared__ float lm[4];
  __shared__ float wsum[4];
  if (lane == 0) lm[wid] = m;
  __syncthreads();
  m = fmaxf(fmaxf(lm[0], lm[1]), fmaxf(lm[2], lm[3]));
  float ex[8], pr[8], run = 0;
#pragma unroll
  for (int i = 0; i < 8; ++i) { ex[i] = __expf(v[i] - m); run += ex[i]; pr[i] = run; }
  float s = run;
  for (int off = 1; off < 64; off <<= 1) {
    float o = __shfl_up(s, off);
    if (lane >= off) s += o;
  }
  if (lane == 63) wsum[wid] = s;
  __syncthreads();
  float base = s - run;  // exclusive prefix of this thread within wave
  for (int jw = 0; jw < wid; ++jw) base += wsum[jw];
#pragma unroll
  for (int i = 0; i < 8; ++i) {
    ee[(size_t)bh * T_ + (tid << 3) + i] = ex[i];
    zz[(size_t)bh * T_ + (tid << 3) + i] = base + pr[i];
  }
}

// ---------------------------------------------------------------------------
// conv: y[b,t,h*64+d] = (1/Z[t]) * sum_{s<=t} e[t-s] * v[s,d]
// block = (t-block of 64) x h x b. thread: td=tid&15 -> d quad, tg=tid>>4 -> t quad.
// ---------------------------------------------------------------------------
__global__ __launch_bounds__(256) void conv_k(const float* __restrict__ qkv,
                                              const float* __restrict__ ee,
                                              const float* __restrict__ zz,
                                              float* __restrict__ y2) {
  __shared__ __align__(16) float sv[64][68];
  __shared__ float se[128];
  const int tid = threadIdx.x;
  const int bx = blockIdx.x, h = blockIdx.y, b = blockIdx.z;
  const int t0 = bx << 6;
  const int td = tid & 15, tg = tid >> 4;
  const int d0 = td << 2;
  const size_t bh = (size_t)b * H_ + h;
  const float* vb = qkv + (size_t)b * T_ * 2304 + 1536 + h * 64;
  const float* ep = ee + bh * T_;
  f32x4 acc0 = {}, acc1 = {}, acc2 = {}, acc3 = {};
  for (int s0 = 0; s0 <= t0; s0 += 64) {
#pragma unroll
    for (int i = 0; i < 4; ++i) {  // stage v[s0..s0+64) x 64d
      int f = tid + (i << 8);
      int row = f >> 4, c4 = (f & 15) << 2;
      *(f32x4*)&sv[row][c4] = *(const f32x4*)(vb + (size_t)(s0 + row) * 2304 + c4);
    }
    const int ebase = t0 - s0 - 63;
    if (tid < 128) {
      int c = ebase + tid;
      se[tid] = (c >= 0 && c < T_) ? ep[c] : 0.0f;
    }
    __syncthreads();
#pragma unroll 4
    for (int s = 0; s < 64; ++s) {
      f32x4 v4 = *(const f32x4*)&sv[s][d0];
      int base = (tg << 2) - s + 63;
      float e0 = se[base + 0];
      float e1 = se[base + 1];
      float e2 = se[base + 2];
      float e3 = se[base + 3];
      acc0 += e0 * v4;
      acc1 += e1 * v4;
      acc2 += e2 * v4;
      acc3 += e3 * v4;
    }
    __syncthreads();
  }
  const float* zp = zz + bh * T_;
#pragma unroll
  for (int i = 0; i < 4; ++i) {
    int t = t0 + (tg << 2) + i;
    float zi = 1.0f / zp[t];
    f32x4 a = (i == 0) ? acc0 : (i == 1) ? acc1 : (i == 2) ? acc2 : acc3;
    f32x4 o = a * zi;
    *(f32x4*)&y2[((size_t)b * T_ + t) * C_ + h * 64 + d0] = o;
  }
}

// ---------------------------------------------------------------------------
extern "C" void kernel_launch(void* const* d_in, const int* in_sizes, int n_in,
                              void* d_out, int out_size, void* d_ws, size_t ws_size,
                              hipStream_t stream) {
  const float* x = (const float*)d_in[0];
  const float* c_attn = (const float*)d_in[1];
  const float* c_proj = (const float*)d_in[2];
  const float* temp = (const float*)d_in[3];
  float* out = (float*)d_out;

  // ws layout (floats): qkv[4096*2304] | cw[24*2048] | e | Z | y2[4096*768]
  float* qkv = (float*)d_ws;
  float* cw = qkv + (size_t)M_ * 2304;
  float* ee = cw + (size_t)B_ * H_ * T_;
  float* zz = ee + (size_t)B_ * H_ * T_;
  float* y2 = zz + (size_t)B_ * H_ * T_;

  gemm_bt<<<dim3(2304 / 128, M_ / 128), 256, 0, stream>>>(x, c_attn, qkv, M_, 2304, C_);
  corr_k<<<dim3(T_ / 64, H_, B_), 256, 0, stream>>>(qkv, temp, cw);
  soft_k<<<dim3(B_ * H_), 256, 0, stream>>>(cw, ee, zz);
  conv_k<<<dim3(T_ / 64, H_, B_), 256, 0, stream>>>(qkv, ee, zz, y2);
  gemm_bt<<<dim3(C_ / 128, M_ / 128), 256, 0, stream>>>(y2, c_proj, out, M_, C_, C_);
}

// Round 2
// 199.421 us; speedup vs baseline: 3.0782x; 3.0782x over previous
//
#include <hip/hip_runtime.h>

#define T_ 2048
#define B_ 2
#define H_ 12
#define C_ 768
#define M_ 4096  // B*T
#define BH_ (B_ * H_)

typedef __attribute__((ext_vector_type(4))) float f32x4;
typedef __attribute__((ext_vector_type(16))) float f32x16;
typedef __attribute__((ext_vector_type(8))) __bf16 bf16x8;
typedef __attribute__((ext_vector_type(4))) __bf16 bf16x4;

// ---------------------------------------------------------------------------
// GEMM: C[M,N] = A[M,K] * B[N,K]^T   (fp32 in, bf16 MFMA, fp32 out)
// ---------------------------------------------------------------------------
__global__ __launch_bounds__(256) void gemm_bt(const float* __restrict__ A,
                                               const float* __restrict__ Bm,
                                               float* __restrict__ C,
                                               int M, int N, int K) {
  __shared__ __align__(16) __bf16 sA[128][40];
  __shared__ __align__(16) __bf16 sB[128][40];
  const int tid = threadIdx.x;
  const int m0 = blockIdx.y * 128, n0 = blockIdx.x * 128;
  const int lane = tid & 63, w = tid >> 6;
  const int wr = w >> 1, wc = w & 1;
  const int fr = lane & 15;
  const int ko = (lane >> 4) << 3;
  f32x4 acc[4][4] = {};
  for (int k0 = 0; k0 < K; k0 += 32) {
#pragma unroll
    for (int i = 0; i < 4; ++i) {
      int f = tid + (i << 8);
      int row = f >> 3, c4 = (f & 7) << 2;
      f32x4 av = *(const f32x4*)(A + (size_t)(m0 + row) * K + k0 + c4);
      f32x4 bv = *(const f32x4*)(Bm + (size_t)(n0 + row) * K + k0 + c4);
      bf16x4 ah, bh;
#pragma unroll
      for (int j = 0; j < 4; ++j) { ah[j] = (__bf16)av[j]; bh[j] = (__bf16)bv[j]; }
      *(bf16x4*)&sA[row][c4] = ah;
      *(bf16x4*)&sB[row][c4] = bh;
    }
    __syncthreads();
    bf16x8 a[4], b[4];
#pragma unroll
    for (int m = 0; m < 4; ++m) a[m] = *(const bf16x8*)&sA[wr * 64 + m * 16 + fr][ko];
#pragma unroll
    for (int n = 0; n < 4; ++n) b[n] = *(const bf16x8*)&sB[wc * 64 + n * 16 + fr][ko];
#pragma unroll
    for (int m = 0; m < 4; ++m)
#pragma unroll
      for (int n = 0; n < 4; ++n)
        acc[m][n] = __builtin_amdgcn_mfma_f32_16x16x32_bf16(a[m], b[n], acc[m][n], 0, 0, 0);
    __syncthreads();
  }
  const int orow = (lane >> 4) << 2, ocol = lane & 15;
#pragma unroll
  for (int m = 0; m < 4; ++m)
#pragma unroll
    for (int n = 0; n < 4; ++n) {
      int r = m0 + wr * 64 + m * 16 + orow;
      int c = n0 + wc * 64 + n * 16 + ocol;
#pragma unroll
      for (int j = 0; j < 4; ++j) C[(size_t)(r + j) * N + c] = acc[m][n][j];
    }
}

// ---------------------------------------------------------------------------
// corr via diagonal-band MFMA.
// S = Q K^T. Band q = ti-si (32-tiles). Wave w owns bands qA=8qb+2w, qA+1,
// accumulating mfma_32x32x16 tiles over ti; lag = 32q + row - col is loop-
// invariant, so diagonal reduction happens ONCE per block into per-wave LDS
// regions, then merged and written to disjoint partial slices P[16][BH][T].
// grid.x = 36 valid (qb,tc) pairs (qb<=tc<8), y=H, z=B.
// ---------------------------------------------------------------------------
__global__ __launch_bounds__(256) void corr_k(const float* __restrict__ qkv,
                                              float* __restrict__ P) {
  __shared__ __align__(16) __bf16 sQ[32][72];
  __shared__ __align__(16) __bf16 sK[8][32][72];
  __shared__ float swc[4][128];
  const int tid = threadIdx.x;
  int idx = blockIdx.x, qb = 0;
  while (idx >= 8 - qb) { idx -= 8 - qb; ++qb; }
  const int tc = qb + idx;
  const int h = blockIdx.y, b = blockIdx.z;
  const int lane = tid & 63, w = tid >> 6;

  for (int i = tid; i < 512; i += 256) ((float*)swc)[i] = 0.f;

  const float* qp = qkv + (size_t)b * T_ * 2304 + h * 64;
  const float* kp = qp + 768;
  const int srow = tid >> 3;         // 0..31
  const int scol = (tid & 7) << 3;   // 0..56

  // prologue: fill ring slots si0-7 .. si0-1 (zeros for si<0)
  const int si0 = 8 * (tc - qb);
  for (int si = si0 - 7; si < si0; ++si) {
    bf16x8 hv = {};
    if (si >= 0) {
      const float* src = kp + (size_t)(32 * si + srow) * 2304 + scol;
      f32x4 v0 = *(const f32x4*)src;
      f32x4 v1 = *(const f32x4*)(src + 4);
#pragma unroll
      for (int j = 0; j < 4; ++j) { hv[j] = (__bf16)v0[j]; hv[4 + j] = (__bf16)v1[j]; }
    }
    *(bf16x8*)&sK[si & 7][srow][scol] = hv;
  }

  const int qA = 8 * qb + 2 * w;
  const int fr = lane & 31, kg = (lane >> 5) << 3;
  f32x16 acc0 = {}, acc1 = {};

  for (int ti = 8 * tc; ti < 8 * tc + 8; ++ti) {
    {  // stage Q[ti] and K slot si = ti - 8*qb (>= 0 here)
      const float* srcq = qp + (size_t)(32 * ti + srow) * 2304 + scol;
      f32x4 q0 = *(const f32x4*)srcq;
      f32x4 q1 = *(const f32x4*)(srcq + 4);
      const float* srck = kp + (size_t)(32 * (ti - 8 * qb) + srow) * 2304 + scol;
      f32x4 k0 = *(const f32x4*)srck;
      f32x4 k1 = *(const f32x4*)(srck + 4);
      bf16x8 hq, hk;
#pragma unroll
      for (int j = 0; j < 4; ++j) {
        hq[j] = (__bf16)q0[j]; hq[4 + j] = (__bf16)q1[j];
        hk[j] = (__bf16)k0[j]; hk[4 + j] = (__bf16)k1[j];
      }
      *(bf16x8*)&sQ[srow][scol] = hq;
      *(bf16x8*)&sK[ti & 7][srow][scol] = hk;
    }
    __syncthreads();
    const __bf16* kA = sK[(ti - qA) & 7][fr];
    const __bf16* kB = sK[(ti - qA - 1) & 7][fr];
    const __bf16* qq = sQ[fr];
#pragma unroll
    for (int kc = 0; kc < 4; ++kc) {
      bf16x8 a = *(const bf16x8*)&qq[kc * 16 + kg];
      bf16x8 bA = *(const bf16x8*)&kA[kc * 16 + kg];
      bf16x8 bB = *(const bf16x8*)&kB[kc * 16 + kg];
      acc0 = __builtin_amdgcn_mfma_f32_32x32x16_bf16(a, bA, acc0, 0, 0, 0);
      acc1 = __builtin_amdgcn_mfma_f32_32x32x16_bf16(a, bB, acc1, 0, 0, 0);
    }
    __syncthreads();
  }

  // diagonal reduction: C layout col=lane&31, row=(j&3)+8*(j>>2)+4*(lane>>5)
  const int col = lane & 31, rb = (lane >> 5) << 2;
#pragma unroll
  for (int j = 0; j < 16; ++j) {
    int row = (j & 3) + ((j >> 2) << 3) + rb;
    atomicAdd(&swc[w][row - col + 31], acc0[j]);   // band qA:   idx = lag-(32qA-31)
    atomicAdd(&swc[w][row - col + 63], acc1[j]);   // band qA+1: +32
  }
  __syncthreads();

  // merge 4 wave regions, write disjoint slice P[(qb&1)*8+tc][bh][L]
  const int bh = b * H_ + h;
  float* Pd = P + ((size_t)((qb & 1) * 8 + tc) * BH_ + bh) * T_;
  for (int ii = tid; ii < 287; ii += 256) {
    int l = ii - 31;             // lag - 256*qb
    int L = 256 * qb + l;
    if (L < 0 || L >= T_) continue;
    float s = 0.f;
    for (int ww = 0; ww < 4; ++ww) {
      int r = l - 64 * ww + 31;  // wave ww covers local lags [64ww-31, 64ww+63]
      if (r >= 0 && r < 95) s += swc[ww][r];
    }
    Pd[L] = s;
  }
}

// ---------------------------------------------------------------------------
// softmax prep per (b,h): reduce 16 partial slices, scale, then
// M = max w; e = exp(w-M); Z[t] = prefix sum of e.
// ---------------------------------------------------------------------------
__global__ __launch_bounds__(256) void soft_k(const float* __restrict__ P,
                                              const float* __restrict__ temp,
                                              float* __restrict__ ee,
                                              float* __restrict__ zz) {
  const int bh = blockIdx.x, tid = threadIdx.x;
  const int lane = tid & 63, wid = tid >> 6;
  const float scale = 1.0f / (64.0f * (temp[0] + 1e-6f));
  f32x4 sa = {}, sb = {};
#pragma unroll
  for (int j = 0; j < 16; ++j) {
    const float* pp = P + ((size_t)j * BH_ + bh) * T_ + (tid << 3);
    sa += *(const f32x4*)pp;
    sb += *(const f32x4*)(pp + 4);
  }
  float v[8];
#pragma unroll
  for (int i = 0; i < 4; ++i) { v[i] = sa[i] * scale; v[4 + i] = sb[i] * scale; }
  float m = v[0];
#pragma unroll
  for (int i = 1; i < 8; ++i) m = fmaxf(m, v[i]);
#pragma unroll
  for (int off = 1; off < 64; off <<= 1) m = fmaxf(m, __shfl_xor(m, off));
  __shared__ float lm[4];
  __shared__ float wsum[4];
  if (lane == 0) lm[wid] = m;
  __syncthreads();
  m = fmaxf(fmaxf(lm[0], lm[1]), fmaxf(lm[2], lm[3]));
  float ex[8], pr[8], run = 0;
#pragma unroll
  for (int i = 0; i < 8; ++i) { ex[i] = __expf(v[i] - m); run += ex[i]; pr[i] = run; }
  float s = run;
  for (int off = 1; off < 64; off <<= 1) {
    float o = __shfl_up(s, off);
    if (lane >= off) s += o;
  }
  if (lane == 63) wsum[wid] = s;
  __syncthreads();
  float base = s - run;
  for (int jw = 0; jw < wid; ++jw) base += wsum[jw];
#pragma unroll
  for (int i = 0; i < 8; ++i) {
    ee[(size_t)bh * T_ + (tid << 3) + i] = ex[i];
    zz[(size_t)bh * T_ + (tid << 3) + i] = base + pr[i];
  }
}

// ---------------------------------------------------------------------------
// conv via Toeplitz MFMA: y[t,d] = (1/Z[t]) * sum_{s<=t} e[t-s] * v[s,d].
// E-operand generated from reversed-e LDS with 8 phase-shifted bf16 copies
// so each A-frag is one aligned ds_read_b128. V transposed into LDS (stride
// 44 -> conflict-free b64 frag reads). grid.x = 16 t-blocks (big first).
// ---------------------------------------------------------------------------
__global__ __launch_bounds__(256) void conv_k(const float* __restrict__ qkv,
                                              const float* __restrict__ ee,
                                              const float* __restrict__ zz,
                                              float* __restrict__ y2) {
  __shared__ __align__(16) __bf16 revc[8][2192];
  __shared__ __align__(16) __bf16 sVt[64][44];
  __shared__ float szinv[128];
  const int tid = threadIdx.x;
  const int tb = 15 - (int)blockIdx.x;
  const int t0 = tb * 128;
  const int h = blockIdx.y, b = blockIdx.z;
  const int lane = tid & 63, w = tid >> 6;
  const size_t bh = (size_t)b * H_ + h;
  const float* ep = ee + bh * T_;
  const float* vp = qkv + (size_t)b * T_ * 2304 + 1536 + h * 64;

  // revc[p][i] = bf16(R[i+p]), R[x] = e[T-1-x] (0 if OOB)
#pragma unroll
  for (int p = 0; p < 8; ++p)
    for (int i = tid; i < 2192; i += 256) {
      int eidx = T_ - 1 - (i + p);
      revc[p][i] = (__bf16)((eidx >= 0) ? ep[eidx] : 0.f);
    }
  if (tid < 128) szinv[tid] = 1.f / zz[bh * T_ + t0 + tid];

  const int fr = lane & 31, kg = (lane >> 5) << 3;
  const int trow = t0 + 32 * w + fr;
  const int pp = (T_ - 1 - trow) & 7;
  const int obase = (T_ - 1 - trow) - pp;
  f32x16 acc0 = {}, acc1 = {};

  for (int s0 = 0; s0 < t0 + 128; s0 += 32) {
    // stage V[s0..s0+32) x 64d transposed
#pragma unroll
    for (int pass = 0; pass < 2; ++pass) {
      int sl = (tid >> 4) + (pass << 4);
      int d0 = (tid & 15) << 2;
      f32x4 v = *(const f32x4*)(vp + (size_t)(s0 + sl) * 2304 + d0);
#pragma unroll
      for (int i2 = 0; i2 < 4; ++i2) sVt[d0 + i2][sl] = (__bf16)v[i2];
    }
    __syncthreads();
#pragma unroll
    for (int kc = 0; kc < 2; ++kc) {
      int off = (kc << 4) + kg;
      bf16x8 a = *(const bf16x8*)&revc[pp][obase + s0 + off];
      bf16x4 lo0 = *(const bf16x4*)&sVt[fr][off];
      bf16x4 hi0 = *(const bf16x4*)&sVt[fr][off + 4];
      bf16x4 lo1 = *(const bf16x4*)&sVt[32 + fr][off];
      bf16x4 hi1 = *(const bf16x4*)&sVt[32 + fr][off + 4];
      bf16x8 b0, b1;
#pragma unroll
      for (int j2 = 0; j2 < 4; ++j2) {
        b0[j2] = lo0[j2]; b0[4 + j2] = hi0[j2];
        b1[j2] = lo1[j2]; b1[4 + j2] = hi1[j2];
      }
      acc0 = __builtin_amdgcn_mfma_f32_32x32x16_bf16(a, b0, acc0, 0, 0, 0);
      acc1 = __builtin_amdgcn_mfma_f32_32x32x16_bf16(a, b1, acc1, 0, 0, 0);
    }
    __syncthreads();
  }

  const int ocol = lane & 31, rb = (lane >> 5) << 2;
#pragma unroll
  for (int j = 0; j < 16; ++j) {
    int row = (j & 3) + ((j >> 2) << 3) + rb;
    int t = t0 + 32 * w + row;
    float zi = szinv[32 * w + row];
    y2[((size_t)b * T_ + t) * C_ + h * 64 + ocol] = acc0[j] * zi;
    y2[((size_t)b * T_ + t) * C_ + h * 64 + 32 + ocol] = acc1[j] * zi;
  }
}

// ---------------------------------------------------------------------------
extern "C" void kernel_launch(void* const* d_in, const int* in_sizes, int n_in,
                              void* d_out, int out_size, void* d_ws, size_t ws_size,
                              hipStream_t stream) {
  const float* x = (const float*)d_in[0];
  const float* c_attn = (const float*)d_in[1];
  const float* c_proj = (const float*)d_in[2];
  const float* temp = (const float*)d_in[3];
  float* out = (float*)d_out;

  // ws layout (floats): qkv[4096*2304] | ee | zz | y2[4096*768]
  // P (16*BH*T = 3 MB of corr partials) aliases y2: consumed by soft_k
  // before conv writes y2. Stream-ordered, re-initialized every call.
  float* qkv = (float*)d_ws;
  float* ee = qkv + (size_t)M_ * 2304;
  float* zz = ee + (size_t)BH_ * T_;
  float* y2 = zz + (size_t)BH_ * T_;
  float* P = y2;

  gemm_bt<<<dim3(2304 / 128, M_ / 128), 256, 0, stream>>>(x, c_attn, qkv, M_, 2304, C_);
  hipMemsetAsync(P, 0, (size_t)16 * BH_ * T_ * sizeof(float), stream);
  corr_k<<<dim3(36, H_, B_), 256, 0, stream>>>(qkv, P);
  soft_k<<<dim3(BH_), 256, 0, stream>>>(P, temp, ee, zz);
  conv_k<<<dim3(16, H_, B_), 256, 0, stream>>>(qkv, ee, zz, y2);
  gemm_bt<<<dim3(C_ / 128, M_ / 128), 256, 0, stream>>>(y2, c_proj, out, M_, C_, C_);
}

// Round 3
// 186.566 us; speedup vs baseline: 3.2903x; 1.0689x over previous
//
#include <hip/hip_runtime.h>

#define T_ 2048
#define B_ 2
#define H_ 12
#define C_ 768
#define M_ 4096  // B*T
#define BH_ (B_ * H_)
#define RSTR 2200  // reversed-e padded stride (phase stride 4400B -> 8 distinct bank groups)

typedef __attribute__((ext_vector_type(4))) float f32x4;
typedef __attribute__((ext_vector_type(16))) float f32x16;
typedef __attribute__((ext_vector_type(8))) __bf16 bf16x8;
typedef __attribute__((ext_vector_type(4))) __bf16 bf16x4;

// ---------------------------------------------------------------------------
// Stage-1 GEMM: qkv = x @ c_attn^T, written DIRECTLY as bf16 packs:
//   Qb,Kb: [bh][T][64]   Vt: [bh][64][T] (transposed)
// ---------------------------------------------------------------------------
__global__ __launch_bounds__(256) void gemm_qkv(const float* __restrict__ A,
                                                const float* __restrict__ Bm,
                                                __bf16* __restrict__ Qb,
                                                __bf16* __restrict__ Kb,
                                                __bf16* __restrict__ Vt) {
  __shared__ __align__(16) __bf16 sA[128][40];
  __shared__ __align__(16) __bf16 sB[128][40];
  const int tid = threadIdx.x;
  const int m0 = blockIdx.y * 128, n0 = blockIdx.x * 128;
  const int lane = tid & 63, w = tid >> 6;
  const int wr = w >> 1, wc = w & 1;
  const int fr = lane & 15;
  const int ko = (lane >> 4) << 3;
  const int K = C_;
  f32x4 acc[4][4] = {};
  for (int k0 = 0; k0 < K; k0 += 32) {
#pragma unroll
    for (int i = 0; i < 4; ++i) {
      int f = tid + (i << 8);
      int row = f >> 3, c4 = (f & 7) << 2;
      f32x4 av = *(const f32x4*)(A + (size_t)(m0 + row) * K + k0 + c4);
      f32x4 bv = *(const f32x4*)(Bm + (size_t)(n0 + row) * K + k0 + c4);
      bf16x4 ah, bh;
#pragma unroll
      for (int j = 0; j < 4; ++j) { ah[j] = (__bf16)av[j]; bh[j] = (__bf16)bv[j]; }
      *(bf16x4*)&sA[row][c4] = ah;
      *(bf16x4*)&sB[row][c4] = bh;
    }
    __syncthreads();
    bf16x8 a[4], b[4];
#pragma unroll
    for (int m = 0; m < 4; ++m) a[m] = *(const bf16x8*)&sA[wr * 64 + m * 16 + fr][ko];
#pragma unroll
    for (int n = 0; n < 4; ++n) b[n] = *(const bf16x8*)&sB[wc * 64 + n * 16 + fr][ko];
#pragma unroll
    for (int m = 0; m < 4; ++m)
#pragma unroll
      for (int n = 0; n < 4; ++n)
        acc[m][n] = __builtin_amdgcn_mfma_f32_16x16x32_bf16(a[m], b[n], acc[m][n], 0, 0, 0);
    __syncthreads();
  }
  const int orow = (lane >> 4) << 2, ocol = lane & 15;
#pragma unroll
  for (int m = 0; m < 4; ++m)
#pragma unroll
    for (int n = 0; n < 4; ++n) {
      int r = m0 + wr * 64 + m * 16 + orow;  // token row (4 consecutive via j)
      int c = n0 + wc * 64 + n * 16 + ocol;  // feature col
      int sec = c / 768;                     // 0=Q 1=K 2=V (16-wide frag never crosses)
      int hd = c - sec * 768;
      int h = hd >> 6, d = hd & 63;
      int b = r >> 11, t = r & 2047;
      size_t bhh = (size_t)b * H_ + h;
      if (sec < 2) {
        __bf16* dst = (sec == 0 ? Qb : Kb) + (bhh * T_ + t) * 64 + d;
#pragma unroll
        for (int j = 0; j < 4; ++j) dst[(size_t)j * 64] = (__bf16)acc[m][n][j];
      } else {
        bf16x4 pk;
#pragma unroll
        for (int j = 0; j < 4; ++j) pk[j] = (__bf16)acc[m][n][j];
        *(bf16x4*)(Vt + (bhh * 64 + d) * T_ + t) = pk;
      }
    }
}

// ---------------------------------------------------------------------------
// Generic GEMM (stage 2): C[M,N] = A[M,K] * B[N,K]^T fp32->bf16 MFMA->fp32
// ---------------------------------------------------------------------------
__global__ __launch_bounds__(256) void gemm_bt(const float* __restrict__ A,
                                               const float* __restrict__ Bm,
                                               float* __restrict__ C,
                                               int M, int N, int K) {
  __shared__ __align__(16) __bf16 sA[128][40];
  __shared__ __align__(16) __bf16 sB[128][40];
  const int tid = threadIdx.x;
  const int m0 = blockIdx.y * 128, n0 = blockIdx.x * 128;
  const int lane = tid & 63, w = tid >> 6;
  const int wr = w >> 1, wc = w & 1;
  const int fr = lane & 15;
  const int ko = (lane >> 4) << 3;
  f32x4 acc[4][4] = {};
  for (int k0 = 0; k0 < K; k0 += 32) {
#pragma unroll
    for (int i = 0; i < 4; ++i) {
      int f = tid + (i << 8);
      int row = f >> 3, c4 = (f & 7) << 2;
      f32x4 av = *(const f32x4*)(A + (size_t)(m0 + row) * K + k0 + c4);
      f32x4 bv = *(const f32x4*)(Bm + (size_t)(n0 + row) * K + k0 + c4);
      bf16x4 ah, bh;
#pragma unroll
      for (int j = 0; j < 4; ++j) { ah[j] = (__bf16)av[j]; bh[j] = (__bf16)bv[j]; }
      *(bf16x4*)&sA[row][c4] = ah;
      *(bf16x4*)&sB[row][c4] = bh;
    }
    __syncthreads();
    bf16x8 a[4], b[4];
#pragma unroll
    for (int m = 0; m < 4; ++m) a[m] = *(const bf16x8*)&sA[wr * 64 + m * 16 + fr][ko];
#pragma unroll
    for (int n = 0; n < 4; ++n) b[n] = *(const bf16x8*)&sB[wc * 64 + n * 16 + fr][ko];
#pragma unroll
    for (int m = 0; m < 4; ++m)
#pragma unroll
      for (int n = 0; n < 4; ++n)
        acc[m][n] = __builtin_amdgcn_mfma_f32_16x16x32_bf16(a[m], b[n], acc[m][n], 0, 0, 0);
    __syncthreads();
  }
  const int orow = (lane >> 4) << 2, ocol = lane & 15;
#pragma unroll
  for (int m = 0; m < 4; ++m)
#pragma unroll
    for (int n = 0; n < 4; ++n) {
      int r = m0 + wr * 64 + m * 16 + orow;
      int c = n0 + wc * 64 + n * 16 + ocol;
#pragma unroll
      for (int j = 0; j < 4; ++j) C[(size_t)(r + j) * N + c] = acc[m][n][j];
    }
}

// ---------------------------------------------------------------------------
// corr: diagonal-band MFMA, fragments loaded DIRECTLY from global bf16 packs
// (16B per frag, L2-hot), next-ti prefetch, no LDS staging / no loop barriers.
// grid = 864 = 8 XCD-slots x (3 bh x 36 (qb,tc) pairs); bh pinned per XCD.
// ---------------------------------------------------------------------------
__global__ __launch_bounds__(256) void corr_k(const __bf16* __restrict__ Qb,
                                              const __bf16* __restrict__ Kb,
                                              float* __restrict__ P) {
  __shared__ float swc[4][128];
  const int tid = threadIdx.x;
  int id = blockIdx.x;
  int sub = id >> 3;
  const int bh = (id & 7) * 3 + sub / 36;
  int x = sub % 36, qb = 0;
  while (x >= 8 - qb) { x -= 8 - qb; ++qb; }
  const int tc = qb + x;
  const int lane = tid & 63, w = tid >> 6;

  for (int i = tid; i < 512; i += 256) ((float*)swc)[i] = 0.f;

  const __bf16* qp = Qb + (size_t)bh * T_ * 64;
  const __bf16* kp = Kb + (size_t)bh * T_ * 64;
  const int fr = lane & 31, kg = (lane >> 5) << 3;
  const int qA = 8 * qb + 2 * w;
  f32x16 acc0 = {}, acc1 = {};
  const bf16x8 zf = {};

  bf16x8 a[4], b0[4], b1[4], an[4], b0n[4], b1n[4];

#define CORR_LD(TI, AA, BB0, BB1)                                           \
  {                                                                         \
    const int ti_ = (TI);                                                   \
    const __bf16* qr = qp + ((size_t)(32 * ti_ + fr) << 6) + kg;            \
    const int s0i = ti_ - qA, s1i = ti_ - qA - 1;                           \
    const __bf16* k0r = kp + ((size_t)(32 * s0i + fr) << 6) + kg;           \
    const __bf16* k1r = kp + ((size_t)(32 * s1i + fr) << 6) + kg;           \
    _Pragma("unroll") for (int kc = 0; kc < 4; ++kc) {                      \
      AA[kc] = *(const bf16x8*)(qr + kc * 16);                              \
      BB0[kc] = (s0i >= 0) ? *(const bf16x8*)(k0r + kc * 16) : zf;          \
      BB1[kc] = (s1i >= 0) ? *(const bf16x8*)(k1r + kc * 16) : zf;          \
    }                                                                       \
  }

  CORR_LD(8 * tc, a, b0, b1);
  for (int ti = 8 * tc; ti < 8 * tc + 8; ++ti) {
    if (ti + 1 < 8 * tc + 8) CORR_LD(ti + 1, an, b0n, b1n);
#pragma unroll
    for (int kc = 0; kc < 4; ++kc) {
      acc0 = __builtin_amdgcn_mfma_f32_32x32x16_bf16(a[kc], b0[kc], acc0, 0, 0, 0);
      acc1 = __builtin_amdgcn_mfma_f32_32x32x16_bf16(a[kc], b1[kc], acc1, 0, 0, 0);
    }
#pragma unroll
    for (int kc = 0; kc < 4; ++kc) { a[kc] = an[kc]; b0[kc] = b0n[kc]; b1[kc] = b1n[kc]; }
  }

  __syncthreads();
  // diagonal reduction: C layout col=lane&31, row=(j&3)+8*(j>>2)+4*(lane>>5)
  const int col = lane & 31, rb = (lane >> 5) << 2;
#pragma unroll
  for (int j = 0; j < 16; ++j) {
    int row = (j & 3) + ((j >> 2) << 3) + rb;
    atomicAdd(&swc[w][row - col + 31], acc0[j]);
    atomicAdd(&swc[w][row - col + 63], acc1[j]);
  }
  __syncthreads();

  const int b = bh / H_, h = bh % H_;
  float* Pd = P + ((size_t)((qb & 1) * 8 + tc) * BH_ + (b * H_ + h)) * T_;
  for (int ii = tid; ii < 287; ii += 256) {
    int l = ii - 31;
    int L = 256 * qb + l;
    if (L < 0 || L >= T_) continue;
    float s = 0.f;
    for (int ww = 0; ww < 4; ++ww) {
      int r = l - 64 * ww + 31;
      if (r >= 0 && r < 95) s += swc[ww][r];
    }
    Pd[L] = s;
  }
}

// ---------------------------------------------------------------------------
// soft_k: reduce 16 partial slices -> softmax pieces. Outputs:
//   Rb [bh][8][RSTR] bf16 : 8 phase-shifted reversed-e arrays (zero padded)
//   zinv [bh][T] fp32     : 1/Z[t]
// ---------------------------------------------------------------------------
__global__ __launch_bounds__(256) void soft_k(const float* __restrict__ P,
                                              const float* __restrict__ temp,
                                              __bf16* __restrict__ Rb,
                                              float* __restrict__ zinv) {
  __shared__ float se[T_];
  __shared__ float lm[4], wsum[4];
  const int bh = blockIdx.x, tid = threadIdx.x;
  const int lane = tid & 63, wid = tid >> 6;
  const float scale = 1.0f / (64.0f * (temp[0] + 1e-6f));
  f32x4 sa = {}, sb = {};
#pragma unroll
  for (int j = 0; j < 16; ++j) {
    const float* pp = P + ((size_t)j * BH_ + bh) * T_ + (tid << 3);
    sa += *(const f32x4*)pp;
    sb += *(const f32x4*)(pp + 4);
  }
  float v[8];
#pragma unroll
  for (int i = 0; i < 4; ++i) { v[i] = sa[i] * scale; v[4 + i] = sb[i] * scale; }
  float m = v[0];
#pragma unroll
  for (int i = 1; i < 8; ++i) m = fmaxf(m, v[i]);
#pragma unroll
  for (int off = 1; off < 64; off <<= 1) m = fmaxf(m, __shfl_xor(m, off));
  if (lane == 0) lm[wid] = m;
  __syncthreads();
  m = fmaxf(fmaxf(lm[0], lm[1]), fmaxf(lm[2], lm[3]));
  float ex[8], pr[8], run = 0;
#pragma unroll
  for (int i = 0; i < 8; ++i) { ex[i] = __expf(v[i] - m); run += ex[i]; pr[i] = run; }
  float s = run;
  for (int off = 1; off < 64; off <<= 1) {
    float o = __shfl_up(s, off);
    if (lane >= off) s += o;
  }
  if (lane == 63) wsum[wid] = s;
  __syncthreads();
  float base = s - run;
  for (int jw = 0; jw < wid; ++jw) base += wsum[jw];
#pragma unroll
  for (int i = 0; i < 8; ++i) {
    int t = (tid << 3) + i;
    zinv[(size_t)bh * T_ + t] = 1.0f / (base + pr[i]);
    se[t] = ex[i];
  }
  __syncthreads();
  __bf16* rb = Rb + (size_t)bh * 8 * RSTR;
  for (int c = tid; c < RSTR / 8; c += 256) {
    int i0 = c << 3;
#pragma unroll
    for (int p = 0; p < 8; ++p) {
      bf16x8 ov;
#pragma unroll
      for (int e = 0; e < 8; ++e) {
        int idx = T_ - 1 - p - (i0 + e);
        ov[e] = (__bf16)((idx >= 0) ? se[idx] : 0.f);
      }
      *(bf16x8*)(rb + p * RSTR + i0) = ov;
    }
  }
}

// ---------------------------------------------------------------------------
// conv: Toeplitz MFMA y[t,d] = (1/Z[t]) sum_{s<=t} e[t-s] v[s,d].
// A-frags from LDS reversed-e (copied once from Rb); B-frags = direct 16B
// global loads from Vt (L2-hot, XCD-pinned bh). Paired t-blocks {i,31-i}
// give every block exactly 66 wave-steps. Per-wave independent s-loops.
// grid = 384 = 8 x (3 bh x 16 pairs).
// ---------------------------------------------------------------------------
__global__ __launch_bounds__(256) void conv_k(const __bf16* __restrict__ Vt,
                                              const __bf16* __restrict__ Rb,
                                              const float* __restrict__ zinv,
                                              float* __restrict__ y2) {
  __shared__ __align__(16) __bf16 revc[8 * RSTR];
  const int tid = threadIdx.x;
  int id = blockIdx.x;
  int sub = id >> 3;
  const int bh = (id & 7) * 3 + (sub >> 4);
  const int pr = sub & 15;
  const int lane = tid & 63, w = tid >> 6;

  const __bf16* rb = Rb + (size_t)bh * 8 * RSTR;
  for (int c = tid; c < RSTR; c += 256)
    *(bf16x8*)&revc[c << 3] = *(const bf16x8*)(rb + ((size_t)c << 3));
  __syncthreads();

  const int fr = lane & 31, kg = (lane >> 5) << 3;
  const int tt = (w < 2) ? (64 * pr + 32 * w) : (64 * (31 - pr) + 32 * (w - 2));
  const int trow = tt + fr;
  const int pp = (T_ - 1 - trow) & 7;
  const int obase = (T_ - 1 - trow) - pp;
  const __bf16* vt = Vt + (size_t)bh * 64 * T_;
  const __bf16* v0r = vt + (size_t)fr * T_ + kg;
  const __bf16* v1r = vt + (size_t)(32 + fr) * T_ + kg;
  f32x16 acc0 = {}, acc1 = {};
  const int nst = (tt >> 6) + 1;

  bf16x8 b0[4], b1[4], b0n[4], b1n[4];
#pragma unroll
  for (int kc = 0; kc < 4; ++kc) {
    b0[kc] = *(const bf16x8*)(v0r + kc * 16);
    b1[kc] = *(const bf16x8*)(v1r + kc * 16);
  }
  for (int st = 0; st < nst; ++st) {
    const int s0 = st << 6;
    if (st + 1 < nst) {
#pragma unroll
      for (int kc = 0; kc < 4; ++kc) {
        b0n[kc] = *(const bf16x8*)(v0r + s0 + 64 + kc * 16);
        b1n[kc] = *(const bf16x8*)(v1r + s0 + 64 + kc * 16);
      }
    }
    const int abase = pp * RSTR + obase + s0 + kg;
#pragma unroll
    for (int kc = 0; kc < 4; ++kc) {
      bf16x8 a = *(const bf16x8*)&revc[abase + kc * 16];
      acc0 = __builtin_amdgcn_mfma_f32_32x32x16_bf16(a, b0[kc], acc0, 0, 0, 0);
      acc1 = __builtin_amdgcn_mfma_f32_32x32x16_bf16(a, b1[kc], acc1, 0, 0, 0);
    }
#pragma unroll
    for (int kc = 0; kc < 4; ++kc) { b0[kc] = b0n[kc]; b1[kc] = b1n[kc]; }
  }

  const int b = bh / H_, h = bh % H_;
  const int ocol = lane & 31, rbj = (lane >> 5) << 2;
  const float* zp = zinv + (size_t)bh * T_;
#pragma unroll
  for (int j = 0; j < 16; ++j) {
    int row = (j & 3) + ((j >> 2) << 3) + rbj;
    int t = tt + row;
    float zi = zp[t];
    float* yr = y2 + ((size_t)b * T_ + t) * C_ + h * 64;
    yr[ocol] = acc0[j] * zi;
    yr[32 + ocol] = acc1[j] * zi;
  }
}

// ---------------------------------------------------------------------------
extern "C" void kernel_launch(void* const* d_in, const int* in_sizes, int n_in,
                              void* d_out, int out_size, void* d_ws, size_t ws_size,
                              hipStream_t stream) {
  const float* x = (const float*)d_in[0];
  const float* c_attn = (const float*)d_in[1];
  const float* c_proj = (const float*)d_in[2];
  const float* temp = (const float*)d_in[3];
  float* out = (float*)d_out;

  // ws layout: Qb|Kb|Vt (bf16 [bh][..]) | Rb (bf16) | zinv | y2 | P  (~38.8 MB)
  __bf16* Qb = (__bf16*)d_ws;
  __bf16* Kb = Qb + (size_t)BH_ * T_ * 64;
  __bf16* Vt = Kb + (size_t)BH_ * T_ * 64;
  __bf16* Rb = Vt + (size_t)BH_ * T_ * 64;
  float* zinv = (float*)(Rb + (size_t)BH_ * 8 * RSTR);
  float* y2 = zinv + (size_t)BH_ * T_;
  float* P = y2 + (size_t)M_ * C_;

  gemm_qkv<<<dim3(2304 / 128, M_ / 128), 256, 0, stream>>>(x, c_attn, Qb, Kb, Vt);
  hipMemsetAsync(P, 0, (size_t)16 * BH_ * T_ * sizeof(float), stream);
  corr_k<<<dim3(864), 256, 0, stream>>>(Qb, Kb, P);
  soft_k<<<dim3(BH_), 256, 0, stream>>>(P, temp, Rb, zinv);
  conv_k<<<dim3(384), 256, 0, stream>>>(Vt, Rb, zinv, y2);
  gemm_bt<<<dim3(C_ / 128, M_ / 128), 256, 0, stream>>>(y2, c_proj, out, M_, C_, C_);
}

// Round 4
// 156.584 us; speedup vs baseline: 3.9203x; 1.1915x over previous
//
#include <hip/hip_runtime.h>

#define T_ 2048
#define B_ 2
#define H_ 12
#define C_ 768
#define M_ 4096  // B*T
#define BH_ (B_ * H_)
#define RSTR 2200  // reversed-e padded stride

typedef __attribute__((ext_vector_type(4))) float f32x4;
typedef __attribute__((ext_vector_type(16))) float f32x16;
typedef __attribute__((ext_vector_type(8))) __bf16 bf16x8;
typedef __attribute__((ext_vector_type(4))) __bf16 bf16x4;

// Packed fragment-major layouts (coalesced MFMA frag loads: addr = base + lane*8 elems):
//  Qp/Kp: [bh][tile=t>>5][kc=d>>4][lane=((d>>3)&1)*32 + (t&31)][j=d&7]   (tile stride 2048)
//  Vp:    [bh][chunk=t>>6][dhalf=d>>5][kc=(t&63)>>4][lane=(((t&63)>>3)&1)*32 + (d&31)][j=t&7]

// ---------------------------------------------------------------------------
// Stage-1 GEMM: qkv = x @ c_attn^T -> packed bf16 Qp, Kp, Vp
// ---------------------------------------------------------------------------
__global__ __launch_bounds__(256) void gemm_qkv(const float* __restrict__ A,
                                                const float* __restrict__ Bm,
                                                __bf16* __restrict__ Qp,
                                                __bf16* __restrict__ Kp,
                                                __bf16* __restrict__ Vp) {
  __shared__ __align__(16) __bf16 sA[128][40];
  __shared__ __align__(16) __bf16 sB[128][40];
  const int tid = threadIdx.x;
  const int m0 = blockIdx.y * 128, n0 = blockIdx.x * 128;
  const int lane = tid & 63, w = tid >> 6;
  const int wr = w >> 1, wc = w & 1;
  const int fr = lane & 15;
  const int ko = (lane >> 4) << 3;
  const int K = C_;
  f32x4 acc[4][4] = {};
  for (int k0 = 0; k0 < K; k0 += 32) {
#pragma unroll
    for (int i = 0; i < 4; ++i) {
      int f = tid + (i << 8);
      int row = f >> 3, c4 = (f & 7) << 2;
      f32x4 av = *(const f32x4*)(A + (size_t)(m0 + row) * K + k0 + c4);
      f32x4 bv = *(const f32x4*)(Bm + (size_t)(n0 + row) * K + k0 + c4);
      bf16x4 ah, bh;
#pragma unroll
      for (int j = 0; j < 4; ++j) { ah[j] = (__bf16)av[j]; bh[j] = (__bf16)bv[j]; }
      *(bf16x4*)&sA[row][c4] = ah;
      *(bf16x4*)&sB[row][c4] = bh;
    }
    __syncthreads();
    bf16x8 a[4], b[4];
#pragma unroll
    for (int m = 0; m < 4; ++m) a[m] = *(const bf16x8*)&sA[wr * 64 + m * 16 + fr][ko];
#pragma unroll
    for (int n = 0; n < 4; ++n) b[n] = *(const bf16x8*)&sB[wc * 64 + n * 16 + fr][ko];
#pragma unroll
    for (int m = 0; m < 4; ++m)
#pragma unroll
      for (int n = 0; n < 4; ++n)
        acc[m][n] = __builtin_amdgcn_mfma_f32_16x16x32_bf16(a[m], b[n], acc[m][n], 0, 0, 0);
    __syncthreads();
  }
  const int orow = (lane >> 4) << 2, ocol = lane & 15;
#pragma unroll
  for (int m = 0; m < 4; ++m)
#pragma unroll
    for (int n = 0; n < 4; ++n) {
      int r = m0 + wr * 64 + m * 16 + orow;  // token (4 consecutive via j)
      int c = n0 + wc * 64 + n * 16 + ocol;  // feature
      int sec = c / 768;
      int hd = c - sec * 768;
      int h = hd >> 6, d = hd & 63;
      int b = r >> 11, t = r & 2047;
      int bh = b * H_ + h;
      if (sec < 2) {
        int tile = t >> 5, rr = t & 31;
        int kc = d >> 4, half = (d >> 3) & 1, dj = d & 7;
        __bf16* dst = (sec == 0 ? Qp : Kp) + ((size_t)bh * 64 + tile) * 2048 +
                      kc * 512 + (half * 32 + rr) * 8 + dj;
#pragma unroll
        for (int j = 0; j < 4; ++j) dst[j * 8] = (__bf16)acc[m][n][j];  // rr+j
      } else {
        int chunk = t >> 6, sk = t & 63;
        int kc = sk >> 4, hf = (sk >> 3) & 1, j0 = sk & 7;  // j0 in {0,4}
        bf16x4 pk;
#pragma unroll
        for (int j = 0; j < 4; ++j) pk[j] = (__bf16)acc[m][n][j];
        *(bf16x4*)(Vp + ((size_t)bh * 32 + chunk) * 4096 + (d >> 5) * 2048 +
                   kc * 512 + (hf * 32 + (d & 31)) * 8 + j0) = pk;
      }
    }
}

// ---------------------------------------------------------------------------
// Stage-2 GEMM: C[M,N] = A[M,K] * B[N,K]^T
// ---------------------------------------------------------------------------
__global__ __launch_bounds__(256) void gemm_bt(const float* __restrict__ A,
                                               const float* __restrict__ Bm,
                                               float* __restrict__ C,
                                               int M, int N, int K) {
  __shared__ __align__(16) __bf16 sA[128][40];
  __shared__ __align__(16) __bf16 sB[128][40];
  const int tid = threadIdx.x;
  const int m0 = blockIdx.y * 128, n0 = blockIdx.x * 128;
  const int lane = tid & 63, w = tid >> 6;
  const int wr = w >> 1, wc = w & 1;
  const int fr = lane & 15;
  const int ko = (lane >> 4) << 3;
  f32x4 acc[4][4] = {};
  for (int k0 = 0; k0 < K; k0 += 32) {
#pragma unroll
    for (int i = 0; i < 4; ++i) {
      int f = tid + (i << 8);
      int row = f >> 3, c4 = (f & 7) << 2;
      f32x4 av = *(const f32x4*)(A + (size_t)(m0 + row) * K + k0 + c4);
      f32x4 bv = *(const f32x4*)(Bm + (size_t)(n0 + row) * K + k0 + c4);
      bf16x4 ah, bh;
#pragma unroll
      for (int j = 0; j < 4; ++j) { ah[j] = (__bf16)av[j]; bh[j] = (__bf16)bv[j]; }
      *(bf16x4*)&sA[row][c4] = ah;
      *(bf16x4*)&sB[row][c4] = bh;
    }
    __syncthreads();
    bf16x8 a[4], b[4];
#pragma unroll
    for (int m = 0; m < 4; ++m) a[m] = *(const bf16x8*)&sA[wr * 64 + m * 16 + fr][ko];
#pragma unroll
    for (int n = 0; n < 4; ++n) b[n] = *(const bf16x8*)&sB[wc * 64 + n * 16 + fr][ko];
#pragma unroll
    for (int m = 0; m < 4; ++m)
#pragma unroll
      for (int n = 0; n < 4; ++n)
        acc[m][n] = __builtin_amdgcn_mfma_f32_16x16x32_bf16(a[m], b[n], acc[m][n], 0, 0, 0);
    __syncthreads();
  }
  const int orow = (lane >> 4) << 2, ocol = lane & 15;
#pragma unroll
  for (int m = 0; m < 4; ++m)
#pragma unroll
    for (int n = 0; n < 4; ++n) {
      int r = m0 + wr * 64 + m * 16 + orow;
      int c = n0 + wc * 64 + n * 16 + ocol;
#pragma unroll
      for (int j = 0; j < 4; ++j) C[(size_t)(r + j) * N + c] = acc[m][n][j];
    }
}

// ---------------------------------------------------------------------------
// corr: diagonal-band MFMA, coalesced packed frag loads, full unroll with
// register double-buffer + rolling-K (band qA+1 reuses band qA's prev frag).
// grid = 864 = 8 XCD x (3 bh x 36 (qb,tc) pairs). Writes full P[36] rows.
// ---------------------------------------------------------------------------
__global__ __launch_bounds__(256) void corr_k(const __bf16* __restrict__ Qp,
                                              const __bf16* __restrict__ Kp,
                                              float* __restrict__ P) {
  __shared__ float swc[4][128];
  const int tid = threadIdx.x;
  int id = blockIdx.x;
  int sub = id >> 3;
  const int bh = (id & 7) * 3 + sub / 36;
  const int pi = sub % 36;
  int x = pi, qb = 0;
  while (x >= 8 - qb) { x -= 8 - qb; ++qb; }
  const int tc = qb + x;
  const int lane = tid & 63, w = tid >> 6;

  for (int i = tid; i < 512; i += 256) ((float*)swc)[i] = 0.f;

  const __bf16* qp = Qp + ((size_t)bh << 17) + (lane << 3);
  const __bf16* kp = Kp + ((size_t)bh << 17) + (lane << 3);
  const int qA = 8 * qb + 2 * w;
  f32x16 acc0 = {}, acc1 = {};
  const bf16x8 zf = {};
  bf16x8 Af[2][4], Kc[2][4], Kpv[4];

  {  // prologue: ti = 8tc frags + prev-K frag
    const int t0 = 8 * tc;
#pragma unroll
    for (int kc = 0; kc < 4; ++kc) Af[0][kc] = *(const bf16x8*)(qp + t0 * 2048 + kc * 512);
    const int s0 = t0 - qA, sm = s0 - 1;
#pragma unroll
    for (int kc = 0; kc < 4; ++kc) {
      Kc[0][kc] = (s0 >= 0) ? *(const bf16x8*)(kp + s0 * 2048 + kc * 512) : zf;
      Kpv[kc] = (sm >= 0) ? *(const bf16x8*)(kp + sm * 2048 + kc * 512) : zf;
    }
  }
#pragma unroll
  for (int ii = 0; ii < 8; ++ii) {
    const int cur = ii & 1, nxt = cur ^ 1;
    if (ii < 7) {
      const int tn = 8 * tc + ii + 1;
      const int sn = tn - qA;
#pragma unroll
      for (int kc = 0; kc < 4; ++kc) {
        Af[nxt][kc] = *(const bf16x8*)(qp + tn * 2048 + kc * 512);
        Kc[nxt][kc] = (sn >= 0) ? *(const bf16x8*)(kp + sn * 2048 + kc * 512) : zf;
      }
    }
#pragma unroll
    for (int kc = 0; kc < 4; ++kc) {
      acc0 = __builtin_amdgcn_mfma_f32_32x32x16_bf16(Af[cur][kc], Kc[cur][kc], acc0, 0, 0, 0);
      acc1 = __builtin_amdgcn_mfma_f32_32x32x16_bf16(Af[cur][kc], Kpv[kc], acc1, 0, 0, 0);
    }
#pragma unroll
    for (int kc = 0; kc < 4; ++kc) Kpv[kc] = Kc[cur][kc];
  }

  __syncthreads();
  const int col = lane & 31, rb = (lane >> 5) << 2;
#pragma unroll
  for (int j = 0; j < 16; ++j) {
    int row = (j & 3) + ((j >> 2) << 3) + rb;
    atomicAdd(&swc[w][row - col + 31], acc0[j]);   // band qA
    atomicAdd(&swc[w][row - col + 63], acc1[j]);   // band qA+1
  }
  __syncthreads();

  // merge wave regions; write FULL row of unique slice pi (zeros elsewhere)
  float* Pd = P + ((size_t)pi * BH_ + bh) * T_;
  float ov[8];
#pragma unroll
  for (int u = 0; u < 8; ++u) {
    int L = (tid << 3) + u;
    int l = L - 256 * qb;
    float s = 0.f;
    if (l >= -31 && l < 256) {
#pragma unroll
      for (int ww = 0; ww < 4; ++ww) {
        int r = l - 64 * ww + 31;
        if (r >= 0 && r < 95) s += swc[ww][r];
      }
    }
    ov[u] = s;
  }
  *(f32x4*)(Pd + (tid << 3)) = *(f32x4*)&ov[0];
  *(f32x4*)(Pd + (tid << 3) + 4) = *(f32x4*)&ov[4];
}

// ---------------------------------------------------------------------------
// soft_k: reduce 36 partial slices -> Rb (8 phase-shifted reversed-e, bf16)
// and zinv = 1/Z.
// ---------------------------------------------------------------------------
__global__ __launch_bounds__(256) void soft_k(const float* __restrict__ P,
                                              const float* __restrict__ temp,
                                              __bf16* __restrict__ Rb,
                                              float* __restrict__ zinv) {
  __shared__ float se[T_];
  __shared__ float lm[4], wsum[4];
  const int bh = blockIdx.x, tid = threadIdx.x;
  const int lane = tid & 63, wid = tid >> 6;
  const float scale = 1.0f / (64.0f * (temp[0] + 1e-6f));
  f32x4 sa = {}, sb = {};
#pragma unroll
  for (int j = 0; j < 36; ++j) {
    const float* pp = P + ((size_t)j * BH_ + bh) * T_ + (tid << 3);
    sa += *(const f32x4*)pp;
    sb += *(const f32x4*)(pp + 4);
  }
  float v[8];
#pragma unroll
  for (int i = 0; i < 4; ++i) { v[i] = sa[i] * scale; v[4 + i] = sb[i] * scale; }
  float m = v[0];
#pragma unroll
  for (int i = 1; i < 8; ++i) m = fmaxf(m, v[i]);
#pragma unroll
  for (int off = 1; off < 64; off <<= 1) m = fmaxf(m, __shfl_xor(m, off));
  if (lane == 0) lm[wid] = m;
  __syncthreads();
  m = fmaxf(fmaxf(lm[0], lm[1]), fmaxf(lm[2], lm[3]));
  float ex[8], pr[8], run = 0;
#pragma unroll
  for (int i = 0; i < 8; ++i) { ex[i] = __expf(v[i] - m); run += ex[i]; pr[i] = run; }
  float s = run;
  for (int off = 1; off < 64; off <<= 1) {
    float o = __shfl_up(s, off);
    if (lane >= off) s += o;
  }
  if (lane == 63) wsum[wid] = s;
  __syncthreads();
  float base = s - run;
  for (int jw = 0; jw < wid; ++jw) base += wsum[jw];
#pragma unroll
  for (int i = 0; i < 8; ++i) {
    int t = (tid << 3) + i;
    zinv[(size_t)bh * T_ + t] = 1.0f / (base + pr[i]);
    se[t] = ex[i];
  }
  __syncthreads();
  __bf16* rb = Rb + (size_t)bh * 8 * RSTR;
  for (int c = tid; c < RSTR / 8; c += 256) {
    int i0 = c << 3;
#pragma unroll
    for (int p = 0; p < 8; ++p) {
      bf16x8 ovv;
#pragma unroll
      for (int e = 0; e < 8; ++e) {
        int idx = T_ - 1 - p - (i0 + e);
        ovv[e] = (__bf16)((idx >= 0) ? se[idx] : 0.f);
      }
      *(bf16x8*)(rb + p * RSTR + i0) = ovv;
    }
  }
}

// ---------------------------------------------------------------------------
// conv: Toeplitz MFMA with coalesced packed-V frag loads + LDS reversed-e.
// Paired t-blocks {i,31-i} load-balance. grid = 384 = 8 x (3 bh x 16 pairs).
// ---------------------------------------------------------------------------
__global__ __launch_bounds__(256) void conv_k(const __bf16* __restrict__ Vp,
                                              const __bf16* __restrict__ Rb,
                                              const float* __restrict__ zinv,
                                              float* __restrict__ y2) {
  __shared__ __align__(16) __bf16 revc[8 * RSTR];
  const int tid = threadIdx.x;
  int id = blockIdx.x;
  int sub = id >> 3;
  const int bh = (id & 7) * 3 + (sub >> 4);
  const int pr = sub & 15;
  const int lane = tid & 63, w = tid >> 6;

  const __bf16* rb = Rb + (size_t)bh * 8 * RSTR;
  for (int c = tid; c < RSTR; c += 256)
    *(bf16x8*)&revc[c << 3] = *(const bf16x8*)(rb + ((size_t)c << 3));
  __syncthreads();

  const int fr = lane & 31, kg = (lane >> 5) << 3;
  const int tt = (w < 2) ? (64 * pr + 32 * w) : (64 * (31 - pr) + 32 * (w - 2));
  const int trow = tt + fr;
  const int pp = (T_ - 1 - trow) & 7;
  const int obase = (T_ - 1 - trow) - pp;
  const __bf16* vpb = Vp + (size_t)bh * 131072 + (lane << 3);
  f32x16 acc0 = {}, acc1 = {};
  const int nst = (tt >> 6) + 1;

  bf16x8 VA0[4], VA1[4], VB0[4], VB1[4];
#define LOADV(D0, D1, CH)                                                     \
  {                                                                           \
    const __bf16* vb_ = vpb + (CH) * 4096;                                    \
    _Pragma("unroll") for (int kc = 0; kc < 4; ++kc) {                        \
      D0[kc] = *(const bf16x8*)(vb_ + kc * 512);                              \
      D1[kc] = *(const bf16x8*)(vb_ + 2048 + kc * 512);                       \
    }                                                                         \
  }
#define MSTEP(S0, S1, ST)                                                     \
  {                                                                           \
    const int ab_ = pp * RSTR + obase + (ST) * 64 + kg;                       \
    _Pragma("unroll") for (int kc = 0; kc < 4; ++kc) {                        \
      bf16x8 a_ = *(const bf16x8*)&revc[ab_ + kc * 16];                       \
      acc0 = __builtin_amdgcn_mfma_f32_32x32x16_bf16(a_, S0[kc], acc0, 0, 0, 0); \
      acc1 = __builtin_amdgcn_mfma_f32_32x32x16_bf16(a_, S1[kc], acc1, 0, 0, 0); \
    }                                                                         \
  }

  LOADV(VA0, VA1, 0);
  int st = 0;
  while (true) {
    if (st + 1 < nst) LOADV(VB0, VB1, st + 1);
    MSTEP(VA0, VA1, st);
    ++st;
    if (st >= nst) break;
    if (st + 1 < nst) LOADV(VA0, VA1, st + 1);
    MSTEP(VB0, VB1, st);
    ++st;
    if (st >= nst) break;
  }

  const int b = bh / H_, h = bh % H_;
  const int ocol = lane & 31, rbj = (lane >> 5) << 2;
  const float* zp = zinv + (size_t)bh * T_;
#pragma unroll
  for (int j = 0; j < 16; ++j) {
    int row = (j & 3) + ((j >> 2) << 3) + rbj;
    int t = tt + row;
    float zi = zp[t];
    float* yr = y2 + ((size_t)b * T_ + t) * C_ + h * 64;
    yr[ocol] = acc0[j] * zi;
    yr[32 + ocol] = acc1[j] * zi;
  }
}

// ---------------------------------------------------------------------------
extern "C" void kernel_launch(void* const* d_in, const int* in_sizes, int n_in,
                              void* d_out, int out_size, void* d_ws, size_t ws_size,
                              hipStream_t stream) {
  const float* x = (const float*)d_in[0];
  const float* c_attn = (const float*)d_in[1];
  const float* c_proj = (const float*)d_in[2];
  const float* temp = (const float*)d_in[3];
  float* out = (float*)d_out;

  // ws: Qp|Kp|Vp (3 x 3.145M bf16) | Rb | zinv | y2 | P36  (~39.7 MB)
  __bf16* Qp = (__bf16*)d_ws;
  __bf16* Kp = Qp + (size_t)BH_ * 64 * 2048;
  __bf16* Vp = Kp + (size_t)BH_ * 64 * 2048;
  __bf16* Rb = Vp + (size_t)BH_ * 32 * 4096;
  float* zinv = (float*)(Rb + (size_t)BH_ * 8 * RSTR);
  float* y2 = zinv + (size_t)BH_ * T_;
  float* P = y2 + (size_t)M_ * C_;

  gemm_qkv<<<dim3(2304 / 128, M_ / 128), 256, 0, stream>>>(x, c_attn, Qp, Kp, Vp);
  corr_k<<<dim3(864), 256, 0, stream>>>(Qp, Kp, P);
  soft_k<<<dim3(BH_), 256, 0, stream>>>(P, temp, Rb, zinv);
  conv_k<<<dim3(384), 256, 0, stream>>>(Vp, Rb, zinv, y2);
  gemm_bt<<<dim3(C_ / 128, M_ / 128), 256, 0, stream>>>(y2, c_proj, out, M_, C_, C_);
}